// Round 7
// baseline (9153.076 us; speedup 1.0000x reference)
//
#include <hip/hip_runtime.h>
#include <stdint.h>

// ---------------------------------------------------------------------------
// Fused spiking-MLP forward: 20 timesteps, B=16384, 784 -> 400 -> 10.
//
// RNG (verified round 2, absmax 0.0): jax threefry PARTITIONABLE semantics:
//   key_t = TF((0,42),(0,t));  element e: bits = x0^x1 of TF(key_t,(0,e));
//   u = bitcast((bits>>9)|0x3f800000)-1;  xi = (x > u).
// fp64 membranes (knife-edge mem>0.5 thresholds; f64 matches np-f64 ref).
//
// Round-7 = R2 skeleton (6.18 ms best; 4 samples/wave, j=lane+64k, uniform
// code path, 16 waves/CU) with ONE change: tile layout [dtq][j][4] so that
// BOTH the tile reads and the staging writes use the hardware-proven
// conflict-free b128 pattern (lane i -> 16 CONTIGUOUS bytes, 4-dword lane
// stride — m97/m134). R6's [j][20] layout put 80 B between lanes and paid
// 2.7e9 bank-conflict cycles; this layout keeps lane addresses contiguous:
//   read : &wt[dtq][lane+64k][0]  (28x ds_read_b128 /wave/tile, was 112 b32)
//   write: &wt[dtq][jj][0]        ( 4x ds_write_b128 /row,      was 16 b32)
// Neuron mapping j=lane+64k, fp64 add order (d ascending), masks, ballots,
// layer 2: BYTE-IDENTICAL to R2 -> absmax stays 0.0.
// R3/R4/R5 lessons: don't change wave organization / occupancy / reg budget.
// ---------------------------------------------------------------------------

#define INDIM  784
#define HID    400
#define ODIM   10
#define TSTEPS 20
#define SPB    16         // samples per block
#define TD     16         // d-tile size
#define NT     49         // 784/16
#define WTJ    448        // padded neuron rows
#define XIW    26         // xi words per sample (25 used, +1 pad)
#define SPW    14         // spike words per sample

__device__ __forceinline__ void tfr(uint32_t& x0, uint32_t& x1, int r) {
  x0 += x1;
  x1 = (x1 << r) | (x1 >> (32 - r));
  x1 ^= x0;
}

__device__ __forceinline__ uint2 tf2x32(uint32_t k0, uint32_t k1,
                                        uint32_t c0, uint32_t c1) {
  uint32_t k2 = k0 ^ k1 ^ 0x1BD11BDAu;
  uint32_t x0 = c0 + k0, x1 = c1 + k1;
  tfr(x0,x1,13); tfr(x0,x1,15); tfr(x0,x1,26); tfr(x0,x1,6);
  x0 += k1; x1 += k2 + 1u;
  tfr(x0,x1,17); tfr(x0,x1,29); tfr(x0,x1,16); tfr(x0,x1,24);
  x0 += k2; x1 += k0 + 2u;
  tfr(x0,x1,13); tfr(x0,x1,15); tfr(x0,x1,26); tfr(x0,x1,6);
  x0 += k0; x1 += k1 + 3u;
  tfr(x0,x1,17); tfr(x0,x1,29); tfr(x0,x1,16); tfr(x0,x1,24);
  x0 += k1; x1 += k2 + 4u;
  tfr(x0,x1,13); tfr(x0,x1,15); tfr(x0,x1,26); tfr(x0,x1,6);
  x0 += k2; x1 += k0 + 5u;
  return make_uint2(x0, x1);
}

__device__ __forceinline__ float bits_to_unif(uint32_t b) {
  return __uint_as_float((b >> 9) | 0x3f800000u) - 1.0f;
}

struct SharedMem {
  // tile: wt[dtq][j][4] floats; d = td*16 + dtq*4 + c. 28672 B.
  float    wt[4][WTJ * 4];
  uint32_t xib[SPB][XIW];   // 1664 B
  uint32_t spk[SPB][SPW];   // 896 B
};                          // 31232 B total -> 4 blocks/CU (VGPR-bound)

__global__ __launch_bounds__(256, 4)
void snn_fused(const float* __restrict__ x,  const float* __restrict__ W1,
               const float* __restrict__ b1, const float* __restrict__ W2,
               const float* __restrict__ b2, float* __restrict__ out) {
  __shared__ SharedMem sh;

  const int tid  = threadIdx.x;
  const int g    = blockIdx.x;           // 0..1023
  const int sg   = tid >> 6;             // wave id = sample group
  const int lane = tid & 63;             // neuron-thread index

  // persistent per-thread layer-1 state: mem1[s][k] for samples 4sg+s,
  // neurons j = lane + 64k (j>=400 are zero-padded dummies)
  double   mem1[4][7];
  uint32_t spv[4];
#pragma unroll
  for (int s = 0; s < 4; ++s) {
    spv[s] = 0u;
#pragma unroll
    for (int k = 0; k < 7; ++k) mem1[s][k] = 0.0;
  }

  // layer-2 ownership: tid<160 -> (sample ls, output lo)
  const int ls = tid / ODIM, lo = tid - ls * ODIM;
  const bool l2on = (tid < SPB * ODIM);
  double m2 = 0.0; int s2 = 0, cnt2 = 0;
  const double b2r = l2on ? (double)b2[lo] : 0.0;

  for (int t = 0; t < TSTEPS; ++t) {
    const uint2 kt = tf2x32(0u, 42u, 0u, (uint32_t)t);

    // ---- xi generation: wave sg produces samples 4sg..4sg+3 ----
#pragma unroll
    for (int s4 = 0; s4 < 4; ++s4) {
      const int q   = 4 * sg + s4;
      const int row = g * SPB + q;
      for (int c = 0; c < 13; ++c) {
        const int d = c * 64 + lane;
        int xb = 0;
        if (d < INDIM) {
          const uint32_t e = (uint32_t)row * (uint32_t)INDIM + (uint32_t)d;
          uint2 r = tf2x32(kt.x, kt.y, 0u, e);
          xb = x[row * INDIM + d] > bits_to_unif(r.x ^ r.y);
        }
        unsigned long long m = __ballot(xb);
        if (lane == 0) {
          sh.xib[q][2*c]     = (uint32_t)m;
          sh.xib[q][2*c + 1] = (uint32_t)(m >> 32);
        }
      }
    }

    // ---- decay + reset (ref: mem*0.2*(1-spike)) ----
#pragma unroll
    for (int s = 0; s < 4; ++s)
#pragma unroll
      for (int k = 0; k < 7; ++k)
        mem1[s][k] = ((spv[s] >> k) & 1u) ? 0.0 : mem1[s][k] * 0.2;

    // ---- layer 1: 49 LDS-staged d-tiles ----
    for (int td = 0; td < NT; ++td) {
      const int d0 = td * TD;
      __syncthreads();   // prev tile consumed by all waves; xib ready (td=0)

      // stage W1[jj][d0:d0+16] -> wt[dtq][jj][0:4]; global reads coalesced
      // 64 B/row, LDS writes 4x ds_write_b128 (contiguous 16 B per lane)
#pragma unroll
      for (int half = 0; half < 2; ++half) {
        const int jj = tid + 256 * half;
        if (jj < WTJ) {
          float4 v0, v1, v2, v3;
          if (jj < HID) {
            const float4* src = (const float4*)(W1 + (size_t)jj * INDIM + d0);
            v0 = src[0]; v1 = src[1]; v2 = src[2]; v3 = src[3];
          } else {
            v0 = v1 = v2 = v3 = make_float4(0.f, 0.f, 0.f, 0.f);
          }
          *(float4*)&sh.wt[0][jj * 4] = v0;
          *(float4*)&sh.wt[1][jj * 4] = v1;
          *(float4*)&sh.wt[2][jj * 4] = v2;
          *(float4*)&sh.wt[3][jj * 4] = v3;
        }
      }
      __syncthreads();

      // masks for this tile (wave-uniform per sample) -> SGPRs
      const int sh16 = (td & 1) * 16;
      uint32_t xw[4];
#pragma unroll
      for (int s = 0; s < 4; ++s)
        xw[s] = (__builtin_amdgcn_readfirstlane(sh.xib[4*sg + s][td >> 1])
                 >> sh16) & 0xFFFFu;

#pragma unroll
      for (int dtq = 0; dtq < 4; ++dtq) {
        // 7x ds_read_b128, conflict-free: lane stride = 16 B contiguous
        float4 w4[7];
#pragma unroll
        for (int k = 0; k < 7; ++k)
          w4[k] = *(const float4*)&sh.wt[dtq][(lane + 64 * k) * 4];
        const float* wf = (const float*)&w4[0];
#pragma unroll
        for (int c = 0; c < 4; ++c) {
          const int bit = dtq * 4 + c;        // d ascending: same order as R2
          double wd[7];
#pragma unroll
          for (int k = 0; k < 7; ++k) wd[k] = (double)wf[4 * k + c];
#pragma unroll
          for (int s = 0; s < 4; ++s) {
            if (xw[s] & (1u << bit)) {        // uniform -> scalar branch
#pragma unroll
              for (int k = 0; k < 7; ++k) mem1[s][k] += wd[k];
            }
          }
        }
      }
    }

    // ---- finalize layer 1: + b1, threshold, pack spikes ----
#pragma unroll
    for (int s = 0; s < 4; ++s) {
      uint32_t msk = 0u;
#pragma unroll
      for (int k = 0; k < 7; ++k) {
        const int j = lane + 64 * k;
        const double bb = (j < HID) ? (double)b1[j] : 0.0;
        mem1[s][k] += bb;
        if (mem1[s][k] > 0.5) msk |= (1u << k);   // pad neurons never fire
      }
      spv[s] = msk;
#pragma unroll
      for (int k = 0; k < 7; ++k) {
        unsigned long long bm = __ballot((msk >> k) & 1u);
        if (lane == 0) {
          sh.spk[4*sg + s][2*k]     = (uint32_t)bm;
          sh.spk[4*sg + s][2*k + 1] = (uint32_t)(bm >> 32);
        }
      }
    }
    __syncthreads();   // spk ready (also orders next-step xib writes)

    // ---- layer 2: 160 pairs, bit-sparse fp64 dot over W2 rows ----
    if (l2on) {
      double a2  = s2 ? 0.0 : m2 * 0.2;
      double dot = 0.0;
      const float* w2r = W2 + lo * HID;
      for (int w = 0; w < 13; ++w) {
        uint32_t bits = sh.spk[ls][w];
        if (w == 12) bits &= 0xFFFFu;     // j in [384,400)
        const int jb = 32 * w;
        while (bits) {
          const int bi = __ffs(bits) - 1;
          bits &= bits - 1u;
          dot += (double)w2r[jb + bi];
        }
      }
      m2 = (a2 + dot) + b2r;
      s2 = (m2 > 0.5) ? 1 : 0;
      cnt2 += s2;
    }
  }

  if (l2on)
    out[(g * SPB + ls) * ODIM + lo] = (float)((double)cnt2 / 20.0);
}

extern "C" void kernel_launch(void* const* d_in, const int* in_sizes, int n_in,
                              void* d_out, int out_size, void* d_ws, size_t ws_size,
                              hipStream_t stream) {
  const float* x  = (const float*)d_in[0];
  const float* W1 = (const float*)d_in[1];
  const float* b1 = (const float*)d_in[2];
  const float* W2 = (const float*)d_in[3];
  const float* b2 = (const float*)d_in[4];
  // d_in[5] = time_window (int, ==20) — compile-time constant here.
  float* out = (float*)d_out;
  hipLaunchKernelGGL(snn_fused, dim3(1024), dim3(256), 0, stream,
                     x, W1, b1, W2, b2, out);
}